// Round 11
// baseline (218.792 us; speedup 1.0000x reference)
//
#include <hip/hip_runtime.h>
#include <hip/hip_bf16.h>
#include <math.h>

#define NN 4096
#define HH 128
#define EE 65536
#define GG 64
#define KSPLIT 8
#define KLEN (NN / KSPLIT)
#define SMEM_GEMM 14336
#define SMEM_ATTN 24576

typedef unsigned short u16;
typedef unsigned int u32;
typedef __bf16 bf16x8 __attribute__((ext_vector_type(8)));
typedef float f32x4 __attribute__((ext_vector_type(4)));

__device__ inline u16 f2b(float f) {
  u32 u = __float_as_uint(f);
  u += 0x7FFFu + ((u >> 16) & 1u);
  return (u16)(u >> 16);
}
__device__ inline u32 pkbf2(float a, float b) {
  __hip_bfloat162 h = __float22bfloat162_rn(float2{a, b});
  u32 u; __builtin_memcpy(&u, &h, 4); return u;
}

// ---------------- one-shot weight transpose + bf16, fused with edge count ----
struct TDesc { const float* src; int Ks, K, M, off; };
struct TPack { TDesc d[13]; };

__global__ __launch_bounds__(256) void transcount_k(TPack P, u16* __restrict__ dst,
    const int* __restrict__ ei, int* cnt) {
  if (blockIdx.x >= 1344) {   // edge histogram part
    int e = (blockIdx.x - 1344)*256 + threadIdx.x;
    atomicAdd(&cnt[ei[EE + e]], 1);
    return;
  }
  int idx = blockIdx.x * 256 + threadIdx.x;
  for (int i = 0; i < 13; i++) {
    int sz = P.d[i].K * P.d[i].M;
    if (idx < sz) {
      int m = idx / P.d[i].K;
      int k = idx - m * P.d[i].K;
      float v = (k < P.d[i].Ks) ? P.d[i].src[(size_t)k * P.d[i].M + m] : 0.f;
      dst[P.d[i].off + idx] = f2b(v);
      return;
    }
    idx -= sz;
  }
}

__global__ __launch_bounds__(256) void scan_k(const int* __restrict__ cnt,
    int* __restrict__ rowptr, int* __restrict__ cursor) {
  __shared__ int tot[256];
  int t = threadIdx.x;
  int base = t * 16;
  int loc[16]; int s = 0;
  #pragma unroll
  for (int i = 0; i < 16; i++) { loc[i] = s; s += cnt[base + i]; }
  tot[t] = s;
  __syncthreads();
  for (int off = 1; off < 256; off <<= 1) {
    int v = (t >= off) ? tot[t - off] : 0;
    __syncthreads();
    tot[t] += v;
    __syncthreads();
  }
  int excl = (t == 0) ? 0 : tot[t - 1];
  #pragma unroll
  for (int i = 0; i < 16; i++) {
    int p = excl + loc[i];
    rowptr[base + i] = p; cursor[base + i] = p;
  }
  if (t == 255) rowptr[NN] = excl + s;
}

// ---------------- bf16 MFMA GEMM device body, tile 32(n) x 64(m), 4 waves ----
// ASTAGE: 0 A | 1 A+A2 | 2 BN1(A)+BN2(A2) (ffn1) | 3 KSPLIT-merge (attn-out)
//         | 4 [x,lap,rw] concat
// EPI: 0 plain(+RELU) | 1 acc+bias+res,+stats | 3 acc+bias+BN(res)+BN(res2),+stats
//      | 4 qkv bf16 epilogue
struct GArgs {
  const float *A, *A2, *A3;
  const u16* Bt;
  const float* bias;
  float* C;
  const float *res, *res2;
  float* stats;
  const float *sbase, *pg1, *pb1, *pg2, *pb2;
  const u16 *opart;          // bf16 attention partials
  const float *lpart;
  u16 *qb, *kb, *vt;
  int K, M;
};

template <int ASTAGE, int EPI, int RELU>
__device__ void mgemm_dev(const GArgs& a, int bx, int by, char* smem) {
  char* Ab = smem;                         // 32x64 u16 swizzled (4KB)
  char* Bb = smem + 4096;                  // 64x64 u16 swizzled (8KB)
  float* affs = (float*)(smem + 12288);    // 512 f (2KB)
  const int tid = threadIdx.x;
  const int n0 = bx * 32, m0 = by * 64;
  const int w = tid >> 6, lane = tid & 63;
  const int g = lane >> 4, li = lane & 15;
  const int wr = w >> 1, wc = w & 1;
  const int K = a.K, M = a.M;

  if (ASTAGE == 2) {
    int plane = tid >> 7, cc = tid & 127;
    const float* st = a.sbase + plane*256;
    const float* gg = plane ? a.pg2 : a.pg1;
    const float* bb = plane ? a.pb2 : a.pb1;
    float mean = st[cc] * (1.f/NN);
    float var  = st[128+cc] * (1.f/NN) - mean*mean;
    float s = rsqrtf(var + 1e-5f) * gg[cc];
    affs[plane*256 + cc]       = s;
    affs[plane*256 + 128 + cc] = bb[cc] - mean*s;
    __syncthreads();
  }

  f32x4 acc0 = {0,0,0,0}, acc1 = {0,0,0,0};
  const int arow = tid >> 3, akseg = (tid & 7) * 8;
  const int bcol = tid >> 2, bkseg = (tid & 3) * 16;

  for (int k0 = 0; k0 < K; k0 += 64) {
    {  // stage A fp32 -> bf16
      float4 a0 = {0,0,0,0}, a1 = {0,0,0,0};
      if (ASTAGE == 4) {
        int n = n0 + arow;
        if (k0 == 0) {
          a0 = *(const float4*)&a.A[(size_t)n*64 + akseg];
          a1 = *(const float4*)&a.A[(size_t)n*64 + akseg + 4];
        } else {
          if (akseg == 0)       { a0 = *(const float4*)&a.A2[(size_t)n*8];
                                  a1 = *(const float4*)&a.A2[(size_t)n*8 + 4]; }
          else if (akseg == 8)  { a0 = *(const float4*)&a.A3[(size_t)n*16];
                                  a1 = *(const float4*)&a.A3[(size_t)n*16 + 4]; }
          else if (akseg == 16) { a0 = *(const float4*)&a.A3[(size_t)n*16 + 8];
                                  a1 = *(const float4*)&a.A3[(size_t)n*16 + 12]; }
        }
      } else if (ASTAGE == 3) {
        int n = n0 + arow, c = k0 + akseg;
        int head = c >> 5, d0 = c & 31;
        float4 o0 = {0,0,0,0}, o1 = {0,0,0,0}; float L = 0.f;
        #pragma unroll
        for (int s = 0; s < KSPLIT; s++) {
          const u16* ob = a.opart + ((size_t)(s*4+head)*NN + n)*32 + d0;
          uint4 xx = *(const uint4*)ob;
          o0.x += __uint_as_float(xx.x << 16);
          o0.y += __uint_as_float(xx.x & 0xffff0000u);
          o0.z += __uint_as_float(xx.y << 16);
          o0.w += __uint_as_float(xx.y & 0xffff0000u);
          o1.x += __uint_as_float(xx.z << 16);
          o1.y += __uint_as_float(xx.z & 0xffff0000u);
          o1.z += __uint_as_float(xx.w << 16);
          o1.w += __uint_as_float(xx.w & 0xffff0000u);
          L += a.lpart[(size_t)(s*4+head)*NN + n];
        }
        float inv = 1.f / L;
        a0 = make_float4(o0.x*inv, o0.y*inv, o0.z*inv, o0.w*inv);
        a1 = make_float4(o1.x*inv, o1.y*inv, o1.z*inv, o1.w*inv);
      } else {
        const float* ap = a.A + (size_t)(n0 + arow) * K + k0 + akseg;
        a0 = *(const float4*)ap; a1 = *(const float4*)(ap + 4);
        if (ASTAGE == 1) {
          const float* p2 = a.A2 + (size_t)(n0 + arow) * K + k0 + akseg;
          float4 c0 = *(const float4*)p2, c1 = *(const float4*)(p2 + 4);
          a0.x += c0.x; a0.y += c0.y; a0.z += c0.z; a0.w += c0.w;
          a1.x += c1.x; a1.y += c1.y; a1.z += c1.z; a1.w += c1.w;
        } else if (ASTAGE == 2) {
          const float* p2 = a.A2 + (size_t)(n0 + arow) * K + k0 + akseg;
          float4 c0 = *(const float4*)p2, c1 = *(const float4*)(p2 + 4);
          const float* af = affs + k0 + akseg;
          float4 s1a = *(const float4*)af,         s1b = *(const float4*)(af + 4);
          float4 t1a = *(const float4*)(af + 128), t1b = *(const float4*)(af + 132);
          float4 s2a = *(const float4*)(af + 256), s2b = *(const float4*)(af + 260);
          float4 t2a = *(const float4*)(af + 384), t2b = *(const float4*)(af + 388);
          a0.x = a0.x*s1a.x + t1a.x + c0.x*s2a.x + t2a.x;
          a0.y = a0.y*s1a.y + t1a.y + c0.y*s2a.y + t2a.y;
          a0.z = a0.z*s1a.z + t1a.z + c0.z*s2a.z + t2a.z;
          a0.w = a0.w*s1a.w + t1a.w + c0.w*s2a.w + t2a.w;
          a1.x = a1.x*s1b.x + t1b.x + c1.x*s2b.x + t2b.x;
          a1.y = a1.y*s1b.y + t1b.y + c1.y*s2b.y + t2b.y;
          a1.z = a1.z*s1b.z + t1b.z + c1.z*s2b.z + t2b.z;
          a1.w = a1.w*s1b.w + t1b.w + c1.w*s2b.w + t2b.w;
        }
      }
      u16 t8[8] = {f2b(a0.x), f2b(a0.y), f2b(a0.z), f2b(a0.w),
                   f2b(a1.x), f2b(a1.y), f2b(a1.z), f2b(a1.w)};
      *(uint4*)(Ab + ((arow*128 + akseg*2) ^ ((arow & 7) << 4))) = *(uint4*)t8;
    }
    {  // stage B (already bf16, [m][k])
      const u16* bp = a.Bt + (size_t)(m0 + bcol) * K + k0 + bkseg;
      uint4 b0 = *(const uint4*)bp;
      uint4 b1 = *(const uint4*)(bp + 8);
      int ba = bcol*128 + bkseg*2;
      int sw = (bcol & 7) << 4;
      *(uint4*)(Bb + (ba ^ sw)) = b0;
      *(uint4*)(Bb + ((ba + 16) ^ sw)) = b1;
    }
    __syncthreads();
    int row = wr*16 + li;
    int cAl = wc*32 + li, cBl = cAl + 16;
    #pragma unroll
    for (int ck = 0; ck < 2; ck++) {
      bf16x8 af = *(const bf16x8*)(Ab + ((row*128 + ck*64 + g*16) ^ ((row & 7) << 4)));
      bf16x8 bf0 = *(const bf16x8*)(Bb + ((cAl*128 + ck*64 + g*16) ^ ((cAl & 7) << 4)));
      bf16x8 bf1 = *(const bf16x8*)(Bb + ((cBl*128 + ck*64 + g*16) ^ ((cBl & 7) << 4)));
      acc0 = __builtin_amdgcn_mfma_f32_16x16x32_bf16(af, bf0, acc0, 0, 0, 0);
      acc1 = __builtin_amdgcn_mfma_f32_16x16x32_bf16(af, bf1, acc1, 0, 0, 0);
    }
    __syncthreads();
  }

  const int colA = m0 + wc*32 + li, colB = colA + 16;
  const int colAl = wc*32 + li, colBl = colAl + 16;
  const int rbase = n0 + wr*16 + 4*g;

  if (EPI == 0) {
    float b0 = a.bias[colA], b1 = a.bias[colB];
    #pragma unroll
    for (int r = 0; r < 4; r++) {
      float v0 = acc0[r] + b0, v1 = acc1[r] + b1;
      if (RELU) { v0 = fmaxf(v0, 0.f); v1 = fmaxf(v1, 0.f); }
      a.C[(size_t)(rbase + r) * M + colA] = v0;
      a.C[(size_t)(rbase + r) * M + colB] = v1;
    }
  } else if (EPI == 1 || EPI == 3) {
    float b0 = a.bias[colA], b1 = a.bias[colB];
    float sA1=0, tA1=0, sA2=0, tA2=0, sB1=0, tB1=0, sB2=0, tB2=0;
    if (EPI == 3) {
      auto mk = [&](int col, float& s1, float& t1, float& s2, float& t2) {
        float m1 = a.sbase[col]*(1.f/NN), v1 = a.sbase[128+col]*(1.f/NN) - m1*m1;
        s1 = rsqrtf(v1 + 1e-5f) * a.pg1[col]; t1 = a.pb1[col] - m1*s1;
        float m2 = a.sbase[256+col]*(1.f/NN), v2 = a.sbase[384+col]*(1.f/NN) - m2*m2;
        s2 = rsqrtf(v2 + 1e-5f) * a.pg2[col]; t2 = a.pb2[col] - m2*s2;
      };
      mk(colA, sA1, tA1, sA2, tA2);
      mk(colB, sB1, tB1, sB2, tB2);
    }
    float s0 = 0, q0 = 0, s1 = 0, q1 = 0;
    #pragma unroll
    for (int r = 0; r < 4; r++) {
      int rw2 = rbase + r;
      float v0, v1;
      if (EPI == 1) {
        v0 = acc0[r] + b0 + a.res[(size_t)rw2 * 128 + colA];
        v1 = acc1[r] + b1 + a.res[(size_t)rw2 * 128 + colB];
      } else {
        v0 = acc0[r] + b0 + a.res[(size_t)rw2*128 + colA]*sA1 + tA1
                          + a.res2[(size_t)rw2*128 + colA]*sA2 + tA2;
        v1 = acc1[r] + b1 + a.res[(size_t)rw2*128 + colB]*sB1 + tB1
                          + a.res2[(size_t)rw2*128 + colB]*sB2 + tB2;
      }
      a.C[(size_t)rw2 * M + colA] = v0;
      a.C[(size_t)rw2 * M + colB] = v1;
      s0 += v0; q0 += v0*v0; s1 += v1; q1 += v1*v1;
    }
    s0 += __shfl_xor(s0, 16); s0 += __shfl_xor(s0, 32);
    q0 += __shfl_xor(q0, 16); q0 += __shfl_xor(q0, 32);
    s1 += __shfl_xor(s1, 16); s1 += __shfl_xor(s1, 32);
    q1 += __shfl_xor(q1, 16); q1 += __shfl_xor(q1, 32);
    float* sred = (float*)smem;
    if (lane < 16) {
      sred[wr*64 + colAl] = s0;  sred[128 + wr*64 + colAl] = q0;
      sred[wr*64 + colBl] = s1;  sred[128 + wr*64 + colBl] = q1;
    }
    __syncthreads();
    if (tid < 128) {
      int c = tid & 63, isq = tid >> 6;
      float v = sred[isq*128 + c] + sred[isq*128 + 64 + c];
      atomicAdd(&a.stats[isq*128 + m0 + c], v);
    }
  } else {  // EPI == 4: qkv epilogue
    const float QS = 0.17677669529663687f * 1.4426950408889634f;
    auto doq = [&](int col, f32x4 acc, float bb) {
      if (col < 128) {
        int hd = col >> 5, d = col & 31;
        #pragma unroll
        for (int r = 0; r < 4; r++)
          a.qb[((size_t)hd*NN + rbase + r)*32 + d] = f2b((acc[r] + bb) * QS);
      } else if (col < 256) {
        int hd = (col - 128) >> 5, d = col & 31;
        #pragma unroll
        for (int r = 0; r < 4; r++)
          a.kb[((size_t)hd*NN + rbase + r)*32 + d] = f2b(acc[r] + bb);
      } else {
        #pragma unroll
        for (int r = 0; r < 4; r++)
          a.vt[(size_t)(col - 256)*NN + rbase + r] = f2b(acc[r] + bb);
      }
    };
    doq(colA, acc0, a.bias[colA]);
    doq(colB, acc1, a.bias[colB]);
  }
}

// ---------------- attention device body: 4 waves, 2 query-frags per wave -----
// block covers 128 queries; K/V LDS double-buffered; bf16 opart output.
__device__ void attn_dev(const u16* __restrict__ qb, const u16* __restrict__ kb,
    const u16* __restrict__ vt, u16* __restrict__ opart,
    float* __restrict__ lpart, int split, int qblk, int head, char* smem) {
  u16* kbuf = (u16*)smem;            // [2][2048]
  u16* vbuf = (u16*)(smem + 8192);   // [2][2048]
  const int tid = threadIdx.x;
  const int w = tid >> 6, lane = tid & 63;
  const int g = lane >> 4, li = lane & 15;
  const int q0 = qblk * 128 + w * 16;
  const int j0 = split * KLEN;

  const bf16x8 qfA = *reinterpret_cast<const bf16x8*>(
      qb + ((size_t)(head*NN) + q0 + li)*32 + g*8);
  const bf16x8 qfB = *reinterpret_cast<const bf16x8*>(
      qb + ((size_t)(head*NN) + q0 + 64 + li)*32 + g*8);

  const int vd = tid >> 3;
  const int vcs = (tid & 7) ^ (vd & 7);
  const u16* kpan = kb + (size_t)head*NN*32;
  const u16* vrow_g = vt + (size_t)(head*32 + vd)*NN;

  f32x4 oA0 = {0,0,0,0}, oA1 = {0,0,0,0};
  f32x4 oB0 = {0,0,0,0}, oB1 = {0,0,0,0};
  const f32x4 zz = {0,0,0,0};
  float lsA = 0.f, lsB = 0.f;
  char* pb = smem + 16384 + w*2048;
  const int swz = (li & 7) << 4;

  {  // prologue: stage step 0 into buf 0
    uint4 kv = *(const uint4*)(kpan + (size_t)j0*32 + tid*8);
    uint4 vv = *(const uint4*)(vrow_g + j0 + vcs*8);
    *((uint4*)kbuf + tid) = kv;
    *((uint4*)vbuf + tid) = vv;
  }
  __syncthreads();

  const int NSTEP = KLEN / 64;
  int cur = 0;
  for (int s = 0; s < NSTEP; s++) {
    int jt = j0 + s*64;
    bool pf = (s + 1 < NSTEP);
    uint4 kv = {0,0,0,0}, vv = {0,0,0,0};
    if (pf) {  // T14: issue next-tile loads early, write after compute
      kv = *(const uint4*)(kpan + (size_t)(jt + 64)*32 + tid*8);
      vv = *(const uint4*)(vrow_g + jt + 64 + vcs*8);
    }
    #pragma unroll
    for (int qq = 0; qq < 2; qq++) {
      const bf16x8 qf = qq ? qfB : qfA;
      f32x4 st[4];
      __builtin_amdgcn_s_setprio(1);
      #pragma unroll
      for (int t = 0; t < 4; t++) {
        bf16x8 kf = *(const bf16x8*)&kbuf[cur*2048 + (t*16 + li)*32 + g*8];
        st[t] = __builtin_amdgcn_mfma_f32_16x16x32_bf16(kf, qf, zz, 0, 0, 0);
      }
      __builtin_amdgcn_s_setprio(0);
      float lloc = 0.f;
      #pragma unroll
      for (int t = 0; t < 4; t++) {
        float p0 = exp2f(st[t][0]), p1 = exp2f(st[t][1]);
        float p2 = exp2f(st[t][2]), p3 = exp2f(st[t][3]);
        lloc += p0 + p1 + p2 + p3;
        uint2 wv2;
        wv2.x = pkbf2(p0, p1);
        wv2.y = pkbf2(p2, p3);
        *(uint2*)(pb + ((li*128 + t*32 + g*8) ^ swz)) = wv2;
      }
      if (qq) lsB += lloc; else lsA += lloc;
      __builtin_amdgcn_s_setprio(1);
      #pragma unroll
      for (int c = 0; c < 2; c++) {
        bf16x8 pa = *(const bf16x8*)(pb + ((li*128 + c*64 + g*16) ^ swz));
        int vs = ((c*4 + g) ^ (li & 7)) << 4;
        bf16x8 vb0 = *(const bf16x8*)((char*)(vbuf + cur*2048) + li*128 + vs);
        bf16x8 vb1 = *(const bf16x8*)((char*)(vbuf + cur*2048) + (16 + li)*128 + vs);
        if (qq) {
          oB0 = __builtin_amdgcn_mfma_f32_16x16x32_bf16(pa, vb0, oB0, 0, 0, 0);
          oB1 = __builtin_amdgcn_mfma_f32_16x16x32_bf16(pa, vb1, oB1, 0, 0, 0);
        } else {
          oA0 = __builtin_amdgcn_mfma_f32_16x16x32_bf16(pa, vb0, oA0, 0, 0, 0);
          oA1 = __builtin_amdgcn_mfma_f32_16x16x32_bf16(pa, vb1, oA1, 0, 0, 0);
        }
      }
      __builtin_amdgcn_s_setprio(0);
    }
    if (pf) {
      *((uint4*)(kbuf + (cur ^ 1)*2048) + tid) = kv;
      *((uint4*)(vbuf + (cur ^ 1)*2048) + tid) = vv;
    }
    __syncthreads();
    cur ^= 1;
  }
  lsA += __shfl_xor(lsA, 16);
  lsA += __shfl_xor(lsA, 32);
  lsB += __shfl_xor(lsB, 16);
  lsB += __shfl_xor(lsB, 32);

  size_t b = (size_t)(split*4 + head)*NN + q0;
  size_t b2 = b + 64;
  #pragma unroll
  for (int r = 0; r < 4; r++) {
    size_t ob = (b + 4*g + r)*32;
    opart[ob + li]      = f2b(oA0[r]);
    opart[ob + 16 + li] = f2b(oA1[r]);
    size_t ob2 = (b2 + 4*g + r)*32;
    opart[ob2 + li]      = f2b(oB0[r]);
    opart[ob2 + 16 + li] = f2b(oB1[r]);
  }
  if (lane < 16) {
    lpart[b + lane]  = lsA;
    lpart[b2 + lane] = lsB;
  }
}

// -------- kernel wrappers (single + fused dispatches) --------
template <int AS, int EP, int RE>
__global__ __launch_bounds__(256) void k_gemm(GArgs a) {
  extern __shared__ char smem[];
  mgemm_dev<AS, EP, RE>(a, blockIdx.x, blockIdx.y, smem);
}

// qkv (blocks 0-767) || CSR gather-sum (blocks 768-1279, 8 nodes each)
__global__ __launch_bounds__(256) void k_qkv_agg(GArgs qa,
    const int* __restrict__ rowptr, const int* __restrict__ elist,
    const float* __restrict__ h, float* __restrict__ agg) {
  extern __shared__ char smem[];
  int b = blockIdx.x;
  if (b < 768) { mgemm_dev<0,4,0>(qa, b & 127, b >> 7, smem); return; }
  b -= 768;
  int c = threadIdx.x & 127, sub = threadIdx.x >> 7;
  #pragma unroll
  for (int i = 0; i < 4; i++) {
    int d = b*8 + sub + i*2;
    int beg = rowptr[d], end = rowptr[d + 1];
    float acc = 0.f;
    for (int j = beg; j < end; j++)
      acc += h[(size_t)elist[j]*HH + c];
    agg[(size_t)d*HH + c] = acc;
  }
}

// attention (blocks 0-1023) || gin layer-1 GEMM (blocks 1024-1279)
__global__ __launch_bounds__(256) void k_attn_gin1(
    const u16* __restrict__ qb, const u16* __restrict__ kb,
    const u16* __restrict__ vt, u16* __restrict__ opart,
    float* __restrict__ lpart, GArgs ga) {
  extern __shared__ char smem[];
  int b = blockIdx.x;
  if (b < 1024) { attn_dev(qb, kb, vt, opart, lpart, b & 7, (b >> 3) & 31, b >> 8, smem); return; }
  b -= 1024;
  mgemm_dev<1,0,1>(ga, b & 127, b >> 7, smem);
}

// gin layer-2 || attn-out (inline KSPLIT merge)
__global__ __launch_bounds__(256) void k_gin2_ao(GArgs g2, GArgs ao) {
  extern __shared__ char smem[];
  int b = blockIdx.x;
  if (b < 256) mgemm_dev<0,1,0>(g2, b & 127, b >> 7, smem);
  else { b -= 256; mgemm_dev<3,1,0>(ao, b & 127, b >> 7, smem); }
}

// scatter (blocks 0-255) || input projection (blocks 256-511)
__global__ __launch_bounds__(256) void k_scat_inp(const int* __restrict__ ei,
    int* cursor, int* __restrict__ elist, GArgs ia) {
  extern __shared__ char smem[];
  int b = blockIdx.x;
  if (b < 256) {
    int e = b*256 + threadIdx.x;
    int d = ei[EE + e];
    int p = atomicAdd(&cursor[d], 1);
    elist[p] = ei[e];
  } else {
    b -= 256;
    mgemm_dev<4,0,0>(ia, b & 127, b >> 7, smem);
  }
}

// ---- BN3 apply (+relu) -> h; optionally pool instead of writing h
__global__ __launch_bounds__(256) void bn3_k(
    const float* __restrict__ out3, const float* __restrict__ stats,
    const float* __restrict__ gamma, const float* __restrict__ beta,
    float* __restrict__ h, const int* __restrict__ batch,
    float* __restrict__ pooled, int dopool) {
  int idx = blockIdx.x*256 + threadIdx.x;
  int c = idx & 127;
  float mean = stats[c] * (1.f/NN);
  float var  = stats[128+c] * (1.f/NN) - mean*mean;
  float rs = rsqrtf(var + 1e-5f);
  float r = fmaxf((out3[idx] - mean) * rs * gamma[c] + beta[c], 0.f);
  if (dopool) atomicAdd(&pooled[batch[idx >> 7]*HH + c], r);
  else        h[idx] = r;
}

// ---------------- fused head MLP: per-graph block ----------------
__global__ __launch_bounds__(128) void head_k(
    const float* __restrict__ pooled,
    const float* __restrict__ Wr1, const float* __restrict__ br1,
    const float* __restrict__ Wr2, const float* __restrict__ br2,
    const float* __restrict__ Wc, const float* __restrict__ bc,
    float* __restrict__ out) {
  __shared__ float bufa[128], bufb[128];
  int g = blockIdx.x, c = threadIdx.x;
  bufa[c] = pooled[g*HH + c];
  __syncthreads();
  float acc = br1[c];
  #pragma unroll 8
  for (int k = 0; k < 128; k++) acc += bufa[k] * Wr1[k*128 + c];
  bufb[c] = fmaxf(acc, 0.f);
  __syncthreads();
  acc = br2[c];
  #pragma unroll 8
  for (int k = 0; k < 128; k++) acc += bufb[k] * Wr2[k*128 + c];
  bufa[c] = fmaxf(acc, 0.f);
  __syncthreads();
  if (c < 10) {
    acc = bc[c];
    #pragma unroll 8
    for (int k = 0; k < 128; k++) acc += bufa[k] * Wc[k*10 + c];
    out[g*10 + c] = acc;
  }
}

extern "C" void kernel_launch(void* const* d_in, const int* in_sizes, int n_in,
                              void* d_out, int out_size, void* d_ws, size_t ws_size,
                              hipStream_t stream) {
  const float* x      = (const float*)d_in[0];
  const float* lap    = (const float*)d_in[1];
  const float* rw     = (const float*)d_in[2];
  const int*   ei     = (const int*)d_in[3];
  const int*   batch  = (const int*)d_in[4];
  const float* Wp     = (const float*)d_in[5];
  const float* bp     = (const float*)d_in[6];
  const float* gin_W1 = (const float*)d_in[7];
  const float* gin_b1 = (const float*)d_in[8];
  const float* gin_W2 = (const float*)d_in[9];
  const float* gin_b2 = (const float*)d_in[10];
  const float* bn1_g  = (const float*)d_in[11];
  const float* bn1_b  = (const float*)d_in[12];
  const float* bn2_g  = (const float*)d_in[13];
  const float* bn2_b  = (const float*)d_in[14];
  const float* bn3_g  = (const float*)d_in[15];
  const float* bn3_b  = (const float*)d_in[16];
  const float* ain_w  = (const float*)d_in[17];
  const float* ain_b  = (const float*)d_in[18];
  const float* aout_w = (const float*)d_in[19];
  const float* aout_b = (const float*)d_in[20];
  const float* mlp_W1 = (const float*)d_in[21];
  const float* mlp_b1 = (const float*)d_in[22];
  const float* mlp_W2 = (const float*)d_in[23];
  const float* mlp_b2 = (const float*)d_in[24];
  const float* Wr1    = (const float*)d_in[25];
  const float* br1    = (const float*)d_in[26];
  const float* Wr2    = (const float*)d_in[27];
  const float* br2    = (const float*)d_in[28];
  const float* Wc     = (const float*)d_in[29];
  const float* bc     = (const float*)d_in[30];
  float* out = (float*)d_out;

  float* w = (float*)d_ws;
  float* h      = w + 0;          // 524288
  float* agg    = w + 524288;     // 524288
  float* gtmp   = w + 1048576;    // 524288
  float* pre1   = w + 1572864;    // 524288
  float* pre2   = w + 2097152;    // 524288
  float* mlph   = w + 2621440;    // 1048576
  float* out3   = w + 3670016;    // 524288
  u16*   opart  = (u16*)(w + 4194304);    // 4M u16 (bf16 partials)
  float* lpart  = w + 8388608;    // 131072
  float* stats  = w + 8519680;    // 1536 (2 layers x 768)   [zero region start]
  float* pooled = w + 8521216;    // 8192
  int*   cnt    = (int*)(w + 8529408);    // 4096             [zero region end]
  int*   rowptr = (int*)(w + 8533504);    // 4104
  int*   cursor = (int*)(w + 8537608);    // 4096
  int*   elist  = (int*)(w + 8541704);    // 65536
  u16*   wts    = (u16*)(w + 8607240);    // 344064 u16
  u16*   qb     = (u16*)(w + 8779272);
  u16*   kb     = (u16*)(w + 9041416);
  u16*   vt     = (u16*)(w + 9303560);

  u16* wpt = wts;
  u16 *qkvWt[2], *g1t[2], *g2t[2], *aot[2], *m1t[2], *m2t[2];
  {
    int off = 16384;
    for (int l = 0; l < 2; l++) {
      qkvWt[l] = wts + off; off += 384*128;
      g1t[l]   = wts + off; off += 128*128;
      g2t[l]   = wts + off; off += 128*128;
      aot[l]   = wts + off; off += 128*128;
      m1t[l]   = wts + off; off += 256*128;
      m2t[l]   = wts + off; off += 128*256;
    }
  }
  TPack tp;
  {
    int ti = 0, toff = 0;
    auto addm = [&](const float* s, int Ks, int Kd, int Md) {
      tp.d[ti].src = s; tp.d[ti].Ks = Ks; tp.d[ti].K = Kd; tp.d[ti].M = Md;
      tp.d[ti].off = toff; toff += Kd * Md; ti++;
    };
    addm(Wp, 88, 128, 128);
    for (int l = 0; l < 2; l++) {
      addm(ain_w + l*HH*384, 128, 128, 384);
      addm(gin_W1 + l*HH*HH, 128, 128, 128);
      addm(gin_W2 + l*HH*HH, 128, 128, 128);
      addm(aout_w + l*HH*HH, 128, 128, 128);
      addm(mlp_W1 + l*HH*256, 128, 128, 256);
      addm(mlp_W2 + l*256*HH, 256, 256, 128);
    }
  }

  auto GA = [&](const float* A, const float* A2, const float* A3, const u16* Bt,
                const float* bias, float* C, const float* res, const float* res2,
                float* st, const float* sb, const float* g1, const float* b1,
                const float* g2, const float* b2, const u16* op, const float* lp,
                u16* q, u16* k, u16* v, int K, int M) {
    GArgs a; a.A=A; a.A2=A2; a.A3=A3; a.Bt=Bt; a.bias=bias; a.C=C; a.res=res;
    a.res2=res2; a.stats=st; a.sbase=sb; a.pg1=g1; a.pb1=b1; a.pg2=g2; a.pb2=b2;
    a.opart=op; a.lpart=lp; a.qb=q; a.kb=k; a.vt=v; a.K=K; a.M=M; return a;
  };

  // one memset: stats(1536) + pooled(8192) + cnt(4096) contiguous
  hipMemsetAsync(stats, 0, 13824*sizeof(float), stream);
  transcount_k<<<1600, 256, 0, stream>>>(tp, wts, ei, cnt);
  scan_k<<<1, 256, 0, stream>>>(cnt, rowptr, cursor);
  // scatter (blocks 0-255) || input projection (blocks 256-511)
  k_scat_inp<<<512, 256, SMEM_GEMM, stream>>>(ei, cursor, elist,
      GA(x, lap, rw, wpt, bp, h, nullptr, nullptr, nullptr, nullptr,
         nullptr, nullptr, nullptr, nullptr, nullptr, nullptr,
         nullptr, nullptr, nullptr, 128, 128));

  for (int l = 0; l < 2; l++) {
    float* st1 = stats + l*768;
    float* st2 = st1 + 256;
    float* st3 = st1 + 512;

    // qkv projection (768 blocks) || CSR gather-sum (512 blocks)
    k_qkv_agg<<<1280, 256, SMEM_GEMM, stream>>>(
        GA(h, nullptr, nullptr, qkvWt[l], ain_b + l*384, nullptr, nullptr,
           nullptr, nullptr, nullptr, nullptr, nullptr, nullptr, nullptr,
           nullptr, nullptr, qb, kb, vt, 128, 384),
        rowptr, elist, h, agg);

    // attention (1024 blocks) || gin layer-1 (256 blocks)
    k_attn_gin1<<<1280, 256, SMEM_ATTN, stream>>>(
        qb, kb, vt, opart, lpart,
        GA(h, agg, nullptr, g1t[l], gin_b1 + l*HH, gtmp, nullptr, nullptr,
           nullptr, nullptr, nullptr, nullptr, nullptr, nullptr,
           nullptr, nullptr, nullptr, nullptr, nullptr, 128, 128));

    // gin layer-2 (+res h, stats1) || attn-out (inline merge, +res h, stats2)
    k_gin2_ao<<<512, 256, SMEM_GEMM, stream>>>(
        GA(gtmp, nullptr, nullptr, g2t[l], gin_b2 + l*HH, pre1, h, nullptr,
           st1, nullptr, nullptr, nullptr, nullptr, nullptr,
           nullptr, nullptr, nullptr, nullptr, nullptr, 128, 128),
        GA(nullptr, nullptr, nullptr, aot[l], aout_b + l*HH, pre2, h, nullptr,
           st2, nullptr, nullptr, nullptr, nullptr, nullptr,
           opart, lpart, nullptr, nullptr, nullptr, 128, 128));

    // FFN1 (BN affines staged from stats)
    k_gemm<2,0,1><<<dim3(128,4), 256, SMEM_GEMM, stream>>>(
        GA(pre1, pre2, nullptr, m1t[l], mlp_b1 + l*256, mlph, nullptr, nullptr,
           nullptr, st1, bn1_g + l*HH, bn1_b + l*HH, bn2_g + l*HH, bn2_b + l*HH,
           nullptr, nullptr, nullptr, nullptr, nullptr, 128, 256));
    // FFN2 (+BN(res)+BN(res2), stats3)
    k_gemm<0,3,0><<<dim3(128,2), 256, SMEM_GEMM, stream>>>(
        GA(mlph, nullptr, nullptr, m2t[l], mlp_b2 + l*HH, out3, pre1, pre2,
           st3, st1, bn1_g + l*HH, bn1_b + l*HH, bn2_g + l*HH, bn2_b + l*HH,
           nullptr, nullptr, nullptr, nullptr, nullptr, 256, 128));
    bn3_k<<<NN*HH/256, 256, 0, stream>>>(out3, st3, bn3_g + l*HH, bn3_b + l*HH,
                                         h, batch, pooled, l == 1);
  }

  head_k<<<GG, 128, 0, stream>>>(pooled, Wr1, br1, Wr2, br2, Wc, bc, out);
}

// Round 12
// 186.737 us; speedup vs baseline: 1.1717x; 1.1717x over previous
//
#include <hip/hip_runtime.h>
#include <hip/hip_bf16.h>
#include <math.h>

#define NN 4096
#define HH 128
#define EE 65536
#define GG 64
#define KSPLIT 8
#define KLEN (NN / KSPLIT)
#define SMEM_GEMM 14336

typedef unsigned short u16;
typedef unsigned int u32;
typedef __bf16 bf16x8 __attribute__((ext_vector_type(8)));
typedef float f32x4 __attribute__((ext_vector_type(4)));

__device__ inline u16 f2b(float f) {
  u32 u = __float_as_uint(f);
  u += 0x7FFFu + ((u >> 16) & 1u);
  return (u16)(u >> 16);
}
__device__ inline u32 pkbf2(float a, float b) {
  __hip_bfloat162 h = __float22bfloat162_rn(float2{a, b});
  u32 u; __builtin_memcpy(&u, &h, 4); return u;
}

// ---------------- one-shot weight transpose + bf16, fused with edge count ----
struct TDesc { const float* src; int Ks, K, M, off; };
struct TPack { TDesc d[13]; };

__global__ __launch_bounds__(256) void transcount_k(TPack P, u16* __restrict__ dst,
    const int* __restrict__ ei, int* cnt) {
  if (blockIdx.x >= 1344) {   // edge histogram part
    int e = (blockIdx.x - 1344)*256 + threadIdx.x;
    atomicAdd(&cnt[ei[EE + e]], 1);
    return;
  }
  int idx = blockIdx.x * 256 + threadIdx.x;
  for (int i = 0; i < 13; i++) {
    int sz = P.d[i].K * P.d[i].M;
    if (idx < sz) {
      int m = idx / P.d[i].K;
      int k = idx - m * P.d[i].K;
      float v = (k < P.d[i].Ks) ? P.d[i].src[(size_t)k * P.d[i].M + m] : 0.f;
      dst[P.d[i].off + idx] = f2b(v);
      return;
    }
    idx -= sz;
  }
}

__global__ __launch_bounds__(256) void scan_k(const int* __restrict__ cnt,
    int* __restrict__ rowptr, int* __restrict__ cursor) {
  __shared__ int tot[256];
  int t = threadIdx.x;
  int base = t * 16;
  int loc[16]; int s = 0;
  #pragma unroll
  for (int i = 0; i < 16; i++) { loc[i] = s; s += cnt[base + i]; }
  tot[t] = s;
  __syncthreads();
  for (int off = 1; off < 256; off <<= 1) {
    int v = (t >= off) ? tot[t - off] : 0;
    __syncthreads();
    tot[t] += v;
    __syncthreads();
  }
  int excl = (t == 0) ? 0 : tot[t - 1];
  #pragma unroll
  for (int i = 0; i < 16; i++) {
    int p = excl + loc[i];
    rowptr[base + i] = p; cursor[base + i] = p;
  }
  if (t == 255) rowptr[NN] = excl + s;
}

// per-layer gather-sum: agg[d] = sum_{e: dst=d} h[src_e]   (no atomics)
__global__ __launch_bounds__(256) void aggcsr_k(const int* __restrict__ rowptr,
    const int* __restrict__ elist, const float* __restrict__ h,
    float* __restrict__ agg) {
  int d = blockIdx.x*2 + (threadIdx.x >> 7);
  int c = threadIdx.x & 127;
  int beg = rowptr[d], end = rowptr[d + 1];
  float acc = 0.f;
  for (int j = beg; j < end; j++)
    acc += h[(size_t)elist[j]*HH + c];
  agg[(size_t)d*HH + c] = acc;
}

// ---------------- bf16 MFMA GEMM device body, tile 32(n) x 64(m), 4 waves ----
// ASTAGE: 0 A | 1 A+A2 | 2 BN1(A)+BN2(A2) (ffn1) | 3 KSPLIT-merge (attn-out)
//         | 4 [x,lap,rw] concat
// EPI: 0 plain(+RELU) | 1 acc+bias+res,+stats | 3 acc+bias+BN(res)+BN(res2),+stats
//      | 4 qkv bf16 epilogue
struct GArgs {
  const float *A, *A2, *A3;
  const u16* Bt;
  const float* bias;
  float* C;
  const float *res, *res2;
  float* stats;
  const float *sbase, *pg1, *pb1, *pg2, *pb2;
  const u16 *opart;          // bf16 attention partials
  const float *lpart;
  u16 *qb, *kb, *vt;
  int K, M;
};

template <int ASTAGE, int EPI, int RELU>
__device__ void mgemm_dev(const GArgs& a, int bx, int by, char* smem) {
  char* Ab = smem;                         // 32x64 u16 swizzled (4KB)
  char* Bb = smem + 4096;                  // 64x64 u16 swizzled (8KB)
  float* affs = (float*)(smem + 12288);    // 512 f (2KB)
  const int tid = threadIdx.x;
  const int n0 = bx * 32, m0 = by * 64;
  const int w = tid >> 6, lane = tid & 63;
  const int g = lane >> 4, li = lane & 15;
  const int wr = w >> 1, wc = w & 1;
  const int K = a.K, M = a.M;

  if (ASTAGE == 2) {
    int plane = tid >> 7, cc = tid & 127;
    const float* st = a.sbase + plane*256;
    const float* gg = plane ? a.pg2 : a.pg1;
    const float* bb = plane ? a.pb2 : a.pb1;
    float mean = st[cc] * (1.f/NN);
    float var  = st[128+cc] * (1.f/NN) - mean*mean;
    float s = rsqrtf(var + 1e-5f) * gg[cc];
    affs[plane*256 + cc]       = s;
    affs[plane*256 + 128 + cc] = bb[cc] - mean*s;
    __syncthreads();
  }

  f32x4 acc0 = {0,0,0,0}, acc1 = {0,0,0,0};
  const int arow = tid >> 3, akseg = (tid & 7) * 8;
  const int bcol = tid >> 2, bkseg = (tid & 3) * 16;

  for (int k0 = 0; k0 < K; k0 += 64) {
    {  // stage A fp32 -> bf16
      float4 a0 = {0,0,0,0}, a1 = {0,0,0,0};
      if (ASTAGE == 4) {
        int n = n0 + arow;
        if (k0 == 0) {
          a0 = *(const float4*)&a.A[(size_t)n*64 + akseg];
          a1 = *(const float4*)&a.A[(size_t)n*64 + akseg + 4];
        } else {
          if (akseg == 0)       { a0 = *(const float4*)&a.A2[(size_t)n*8];
                                  a1 = *(const float4*)&a.A2[(size_t)n*8 + 4]; }
          else if (akseg == 8)  { a0 = *(const float4*)&a.A3[(size_t)n*16];
                                  a1 = *(const float4*)&a.A3[(size_t)n*16 + 4]; }
          else if (akseg == 16) { a0 = *(const float4*)&a.A3[(size_t)n*16 + 8];
                                  a1 = *(const float4*)&a.A3[(size_t)n*16 + 12]; }
        }
      } else if (ASTAGE == 3) {
        int n = n0 + arow, c = k0 + akseg;
        int head = c >> 5, d0 = c & 31;
        float4 o0 = {0,0,0,0}, o1 = {0,0,0,0}; float L = 0.f;
        #pragma unroll
        for (int s = 0; s < KSPLIT; s++) {
          const u16* ob = a.opart + ((size_t)(s*4+head)*NN + n)*32 + d0;
          uint4 xx = *(const uint4*)ob;
          o0.x += __uint_as_float(xx.x << 16);
          o0.y += __uint_as_float(xx.x & 0xffff0000u);
          o0.z += __uint_as_float(xx.y << 16);
          o0.w += __uint_as_float(xx.y & 0xffff0000u);
          o1.x += __uint_as_float(xx.z << 16);
          o1.y += __uint_as_float(xx.z & 0xffff0000u);
          o1.z += __uint_as_float(xx.w << 16);
          o1.w += __uint_as_float(xx.w & 0xffff0000u);
          L += a.lpart[(size_t)(s*4+head)*NN + n];
        }
        float inv = 1.f / L;
        a0 = make_float4(o0.x*inv, o0.y*inv, o0.z*inv, o0.w*inv);
        a1 = make_float4(o1.x*inv, o1.y*inv, o1.z*inv, o1.w*inv);
      } else {
        const float* ap = a.A + (size_t)(n0 + arow) * K + k0 + akseg;
        a0 = *(const float4*)ap; a1 = *(const float4*)(ap + 4);
        if (ASTAGE == 1) {
          const float* p2 = a.A2 + (size_t)(n0 + arow) * K + k0 + akseg;
          float4 c0 = *(const float4*)p2, c1 = *(const float4*)(p2 + 4);
          a0.x += c0.x; a0.y += c0.y; a0.z += c0.z; a0.w += c0.w;
          a1.x += c1.x; a1.y += c1.y; a1.z += c1.z; a1.w += c1.w;
        } else if (ASTAGE == 2) {
          const float* p2 = a.A2 + (size_t)(n0 + arow) * K + k0 + akseg;
          float4 c0 = *(const float4*)p2, c1 = *(const float4*)(p2 + 4);
          const float* af = affs + k0 + akseg;
          float4 s1a = *(const float4*)af,         s1b = *(const float4*)(af + 4);
          float4 t1a = *(const float4*)(af + 128), t1b = *(const float4*)(af + 132);
          float4 s2a = *(const float4*)(af + 256), s2b = *(const float4*)(af + 260);
          float4 t2a = *(const float4*)(af + 384), t2b = *(const float4*)(af + 388);
          a0.x = a0.x*s1a.x + t1a.x + c0.x*s2a.x + t2a.x;
          a0.y = a0.y*s1a.y + t1a.y + c0.y*s2a.y + t2a.y;
          a0.z = a0.z*s1a.z + t1a.z + c0.z*s2a.z + t2a.z;
          a0.w = a0.w*s1a.w + t1a.w + c0.w*s2a.w + t2a.w;
          a1.x = a1.x*s1b.x + t1b.x + c1.x*s2b.x + t2b.x;
          a1.y = a1.y*s1b.y + t1b.y + c1.y*s2b.y + t2b.y;
          a1.z = a1.z*s1b.z + t1b.z + c1.z*s2b.z + t2b.z;
          a1.w = a1.w*s1b.w + t1b.w + c1.w*s2b.w + t2b.w;
        }
      }
      u16 t8[8] = {f2b(a0.x), f2b(a0.y), f2b(a0.z), f2b(a0.w),
                   f2b(a1.x), f2b(a1.y), f2b(a1.z), f2b(a1.w)};
      *(uint4*)(Ab + ((arow*128 + akseg*2) ^ ((arow & 7) << 4))) = *(uint4*)t8;
    }
    {  // stage B (already bf16, [m][k])
      const u16* bp = a.Bt + (size_t)(m0 + bcol) * K + k0 + bkseg;
      uint4 b0 = *(const uint4*)bp;
      uint4 b1 = *(const uint4*)(bp + 8);
      int ba = bcol*128 + bkseg*2;
      int sw = (bcol & 7) << 4;
      *(uint4*)(Bb + (ba ^ sw)) = b0;
      *(uint4*)(Bb + ((ba + 16) ^ sw)) = b1;
    }
    __syncthreads();
    int row = wr*16 + li;
    int cAl = wc*32 + li, cBl = cAl + 16;
    #pragma unroll
    for (int ck = 0; ck < 2; ck++) {
      bf16x8 af = *(const bf16x8*)(Ab + ((row*128 + ck*64 + g*16) ^ ((row & 7) << 4)));
      bf16x8 bf0 = *(const bf16x8*)(Bb + ((cAl*128 + ck*64 + g*16) ^ ((cAl & 7) << 4)));
      bf16x8 bf1 = *(const bf16x8*)(Bb + ((cBl*128 + ck*64 + g*16) ^ ((cBl & 7) << 4)));
      acc0 = __builtin_amdgcn_mfma_f32_16x16x32_bf16(af, bf0, acc0, 0, 0, 0);
      acc1 = __builtin_amdgcn_mfma_f32_16x16x32_bf16(af, bf1, acc1, 0, 0, 0);
    }
    __syncthreads();
  }

  const int colA = m0 + wc*32 + li, colB = colA + 16;
  const int colAl = wc*32 + li, colBl = colAl + 16;
  const int rbase = n0 + wr*16 + 4*g;

  if (EPI == 0) {
    float b0 = a.bias[colA], b1 = a.bias[colB];
    #pragma unroll
    for (int r = 0; r < 4; r++) {
      float v0 = acc0[r] + b0, v1 = acc1[r] + b1;
      if (RELU) { v0 = fmaxf(v0, 0.f); v1 = fmaxf(v1, 0.f); }
      a.C[(size_t)(rbase + r) * M + colA] = v0;
      a.C[(size_t)(rbase + r) * M + colB] = v1;
    }
  } else if (EPI == 1 || EPI == 3) {
    float b0 = a.bias[colA], b1 = a.bias[colB];
    float sA1=0, tA1=0, sA2=0, tA2=0, sB1=0, tB1=0, sB2=0, tB2=0;
    if (EPI == 3) {
      auto mk = [&](int col, float& s1, float& t1, float& s2, float& t2) {
        float m1 = a.sbase[col]*(1.f/NN), v1 = a.sbase[128+col]*(1.f/NN) - m1*m1;
        s1 = rsqrtf(v1 + 1e-5f) * a.pg1[col]; t1 = a.pb1[col] - m1*s1;
        float m2 = a.sbase[256+col]*(1.f/NN), v2 = a.sbase[384+col]*(1.f/NN) - m2*m2;
        s2 = rsqrtf(v2 + 1e-5f) * a.pg2[col]; t2 = a.pb2[col] - m2*s2;
      };
      mk(colA, sA1, tA1, sA2, tA2);
      mk(colB, sB1, tB1, sB2, tB2);
    }
    float s0 = 0, q0 = 0, s1 = 0, q1 = 0;
    #pragma unroll
    for (int r = 0; r < 4; r++) {
      int rw2 = rbase + r;
      float v0, v1;
      if (EPI == 1) {
        v0 = acc0[r] + b0 + a.res[(size_t)rw2 * 128 + colA];
        v1 = acc1[r] + b1 + a.res[(size_t)rw2 * 128 + colB];
      } else {
        v0 = acc0[r] + b0 + a.res[(size_t)rw2*128 + colA]*sA1 + tA1
                          + a.res2[(size_t)rw2*128 + colA]*sA2 + tA2;
        v1 = acc1[r] + b1 + a.res[(size_t)rw2*128 + colB]*sB1 + tB1
                          + a.res2[(size_t)rw2*128 + colB]*sB2 + tB2;
      }
      a.C[(size_t)rw2 * M + colA] = v0;
      a.C[(size_t)rw2 * M + colB] = v1;
      s0 += v0; q0 += v0*v0; s1 += v1; q1 += v1*v1;
    }
    s0 += __shfl_xor(s0, 16); s0 += __shfl_xor(s0, 32);
    q0 += __shfl_xor(q0, 16); q0 += __shfl_xor(q0, 32);
    s1 += __shfl_xor(s1, 16); s1 += __shfl_xor(s1, 32);
    q1 += __shfl_xor(q1, 16); q1 += __shfl_xor(q1, 32);
    float* sred = (float*)smem;
    if (lane < 16) {
      sred[wr*64 + colAl] = s0;  sred[128 + wr*64 + colAl] = q0;
      sred[wr*64 + colBl] = s1;  sred[128 + wr*64 + colBl] = q1;
    }
    __syncthreads();
    if (tid < 128) {
      int c = tid & 63, isq = tid >> 6;
      float v = sred[isq*128 + c] + sred[isq*128 + 64 + c];
      atomicAdd(&a.stats[isq*128 + m0 + c], v);
    }
  } else {  // EPI == 4: qkv epilogue
    const float QS = 0.17677669529663687f * 1.4426950408889634f;
    auto doq = [&](int col, f32x4 acc, float bb) {
      if (col < 128) {
        int hd = col >> 5, d = col & 31;
        #pragma unroll
        for (int r = 0; r < 4; r++)
          a.qb[((size_t)hd*NN + rbase + r)*32 + d] = f2b((acc[r] + bb) * QS);
      } else if (col < 256) {
        int hd = (col - 128) >> 5, d = col & 31;
        #pragma unroll
        for (int r = 0; r < 4; r++)
          a.kb[((size_t)hd*NN + rbase + r)*32 + d] = f2b(acc[r] + bb);
      } else {
        #pragma unroll
        for (int r = 0; r < 4; r++)
          a.vt[(size_t)(col - 256)*NN + rbase + r] = f2b(acc[r] + bb);
      }
    };
    doq(colA, acc0, a.bias[colA]);
    doq(colB, acc1, a.bias[colB]);
  }
}

// -------- kernel wrappers (single + fused-pair dispatches) --------
template <int AS, int EP, int RE>
__global__ __launch_bounds__(256) void k_gemm(GArgs a) {
  extern __shared__ char smem[];
  mgemm_dev<AS, EP, RE>(a, blockIdx.x, blockIdx.y, smem);
}

__global__ __launch_bounds__(256) void k_qkv_gin1(GArgs qa, GArgs ga) {
  extern __shared__ char smem[];
  int b = blockIdx.x;
  if (b < 768) mgemm_dev<0,4,0>(qa, b & 127, b >> 7, smem);
  else { b -= 768; mgemm_dev<1,0,1>(ga, b & 127, b >> 7, smem); }
}

__global__ __launch_bounds__(256) void k_gin2_ao(GArgs g2, GArgs ao) {
  extern __shared__ char smem[];
  int b = blockIdx.x;
  if (b < 256) mgemm_dev<0,1,0>(g2, b & 127, b >> 7, smem);
  else { b -= 256; mgemm_dev<3,1,0>(ao, b & 127, b >> 7, smem); }
}

__global__ __launch_bounds__(256) void k_scat_inp(const int* __restrict__ ei,
    int* cursor, int* __restrict__ elist, GArgs ia) {
  extern __shared__ char smem[];
  int b = blockIdx.x;
  if (b < 256) {
    int e = b*256 + threadIdx.x;
    int d = ei[EE + e];
    int p = atomicAdd(&cursor[d], 1);
    elist[p] = ei[e];
  } else {
    b -= 256;
    mgemm_dev<4,0,0>(ia, b & 127, b >> 7, smem);
  }
}

// ---- BN3 apply (+relu) -> h; optionally pool instead of writing h
__global__ __launch_bounds__(256) void bn3_k(
    const float* __restrict__ out3, const float* __restrict__ stats,
    const float* __restrict__ gamma, const float* __restrict__ beta,
    float* __restrict__ h, const int* __restrict__ batch,
    float* __restrict__ pooled, int dopool) {
  int idx = blockIdx.x*256 + threadIdx.x;
  int c = idx & 127;
  float mean = stats[c] * (1.f/NN);
  float var  = stats[128+c] * (1.f/NN) - mean*mean;
  float rs = rsqrtf(var + 1e-5f);
  float r = fmaxf((out3[idx] - mean) * rs * gamma[c] + beta[c], 0.f);
  if (dopool) atomicAdd(&pooled[batch[idx >> 7]*HH + c], r);
  else        h[idx] = r;
}

// ---------------- MFMA flash attention: 4 waves, 2 query-frags per wave ------
// grid (KSPLIT, NN/128, 4 heads), block 256. Block covers 128 queries:
// wave w handles queries [w*16, w*16+16) (frag A) and [64+w*16, ...) (frag B),
// sharing the block's K/V LDS tiles. bf16 opart output.
__global__ __launch_bounds__(256) void mfma_attn_k(
    const u16* __restrict__ qb, const u16* __restrict__ kb,
    const u16* __restrict__ vt, u16* __restrict__ opart,
    float* __restrict__ lpart) {
  __shared__ __align__(16) u16 kbuf[2][2048];   // [64 keys][32 d] linear
  __shared__ __align__(16) u16 vbuf[2][2048];   // [32 d][64 keys] src-swizzled
  __shared__ __align__(16) u16 pbuf[4][1024];   // per-wave, reused A then B

  const int tid = threadIdx.x;
  const int w = tid >> 6, lane = tid & 63;
  const int g = lane >> 4, li = lane & 15;
  const int head = blockIdx.z;
  const int q0 = blockIdx.y * 128 + w * 16;
  const int j0 = blockIdx.x * KLEN;

  const bf16x8 qfA = *reinterpret_cast<const bf16x8*>(
      qb + ((size_t)(head*NN) + q0 + li)*32 + g*8);
  const bf16x8 qfB = *reinterpret_cast<const bf16x8*>(
      qb + ((size_t)(head*NN) + q0 + 64 + li)*32 + g*8);

  const int vd = tid >> 3;
  const int vcs = (tid & 7) ^ (vd & 7);
  const u16* kpan = kb + (size_t)head*NN*32;
  const u16* vrow_g = vt + (size_t)(head*32 + vd)*NN;

  f32x4 oA0 = {0,0,0,0}, oA1 = {0,0,0,0};
  f32x4 oB0 = {0,0,0,0}, oB1 = {0,0,0,0};
  const f32x4 zz = {0,0,0,0};
  float lsA = 0.f, lsB = 0.f;
  char* pb = (char*)&pbuf[w][0];
  const int swz = (li & 7) << 4;

  {  // prologue: stage step 0 into buf 0
    uint4 kv = *(const uint4*)(kpan + (size_t)j0*32 + tid*8);
    uint4 vv = *(const uint4*)(vrow_g + j0 + vcs*8);
    *((uint4*)kbuf[0] + tid) = kv;
    *((uint4*)vbuf[0] + tid) = vv;
  }
  __syncthreads();

  const int NSTEP = KLEN / 64;
  int cur = 0;
  for (int s = 0; s < NSTEP; s++) {
    int jt = j0 + s*64;
    bool pf = (s + 1 < NSTEP);
    uint4 kv = {0,0,0,0}, vv = {0,0,0,0};
    if (pf) {  // T14: issue next-tile loads early, write after compute
      kv = *(const uint4*)(kpan + (size_t)(jt + 64)*32 + tid*8);
      vv = *(const uint4*)(vrow_g + jt + 64 + vcs*8);
    }
    #pragma unroll
    for (int qq = 0; qq < 2; qq++) {
      const bf16x8 qf = qq ? qfB : qfA;
      f32x4 st[4];
      __builtin_amdgcn_s_setprio(1);
      #pragma unroll
      for (int t = 0; t < 4; t++) {
        bf16x8 kf = *(const bf16x8*)&kbuf[cur][(t*16 + li)*32 + g*8];
        st[t] = __builtin_amdgcn_mfma_f32_16x16x32_bf16(kf, qf, zz, 0, 0, 0);
      }
      __builtin_amdgcn_s_setprio(0);
      float lloc = 0.f;
      #pragma unroll
      for (int t = 0; t < 4; t++) {
        float p0 = exp2f(st[t][0]), p1 = exp2f(st[t][1]);
        float p2 = exp2f(st[t][2]), p3 = exp2f(st[t][3]);
        lloc += p0 + p1 + p2 + p3;
        uint2 wv2;
        wv2.x = pkbf2(p0, p1);
        wv2.y = pkbf2(p2, p3);
        *(uint2*)(pb + ((li*128 + t*32 + g*8) ^ swz)) = wv2;
      }
      if (qq) lsB += lloc; else lsA += lloc;
      __builtin_amdgcn_s_setprio(1);
      #pragma unroll
      for (int c = 0; c < 2; c++) {
        bf16x8 pa = *(const bf16x8*)(pb + ((li*128 + c*64 + g*16) ^ swz));
        int vs = ((c*4 + g) ^ (li & 7)) << 4;
        bf16x8 vb0 = *(const bf16x8*)((char*)vbuf[cur] + li*128 + vs);
        bf16x8 vb1 = *(const bf16x8*)((char*)vbuf[cur] + (16 + li)*128 + vs);
        if (qq) {
          oB0 = __builtin_amdgcn_mfma_f32_16x16x32_bf16(pa, vb0, oB0, 0, 0, 0);
          oB1 = __builtin_amdgcn_mfma_f32_16x16x32_bf16(pa, vb1, oB1, 0, 0, 0);
        } else {
          oA0 = __builtin_amdgcn_mfma_f32_16x16x32_bf16(pa, vb0, oA0, 0, 0, 0);
          oA1 = __builtin_amdgcn_mfma_f32_16x16x32_bf16(pa, vb1, oA1, 0, 0, 0);
        }
      }
      __builtin_amdgcn_s_setprio(0);
    }
    if (pf) {
      *((uint4*)kbuf[cur ^ 1] + tid) = kv;
      *((uint4*)vbuf[cur ^ 1] + tid) = vv;
    }
    __syncthreads();
    cur ^= 1;
  }
  lsA += __shfl_xor(lsA, 16);
  lsA += __shfl_xor(lsA, 32);
  lsB += __shfl_xor(lsB, 16);
  lsB += __shfl_xor(lsB, 32);

  size_t b = (size_t)(blockIdx.x*4 + head)*NN + q0;
  size_t b2 = b + 64;
  #pragma unroll
  for (int r = 0; r < 4; r++) {
    size_t ob = (b + 4*g + r)*32;
    opart[ob + li]      = f2b(oA0[r]);
    opart[ob + 16 + li] = f2b(oA1[r]);
    size_t ob2 = (b2 + 4*g + r)*32;
    opart[ob2 + li]      = f2b(oB0[r]);
    opart[ob2 + 16 + li] = f2b(oB1[r]);
  }
  if (lane < 16) {
    lpart[b + lane]  = lsA;
    lpart[b2 + lane] = lsB;
  }
}

// ---------------- fused head MLP: per-graph block ----------------
__global__ __launch_bounds__(128) void head_k(
    const float* __restrict__ pooled,
    const float* __restrict__ Wr1, const float* __restrict__ br1,
    const float* __restrict__ Wr2, const float* __restrict__ br2,
    const float* __restrict__ Wc, const float* __restrict__ bc,
    float* __restrict__ out) {
  __shared__ float bufa[128], bufb[128];
  int g = blockIdx.x, c = threadIdx.x;
  bufa[c] = pooled[g*HH + c];
  __syncthreads();
  float acc = br1[c];
  #pragma unroll 8
  for (int k = 0; k < 128; k++) acc += bufa[k] * Wr1[k*128 + c];
  bufb[c] = fmaxf(acc, 0.f);
  __syncthreads();
  acc = br2[c];
  #pragma unroll 8
  for (int k = 0; k < 128; k++) acc += bufb[k] * Wr2[k*128 + c];
  bufa[c] = fmaxf(acc, 0.f);
  __syncthreads();
  if (c < 10) {
    acc = bc[c];
    #pragma unroll 8
    for (int k = 0; k < 128; k++) acc += bufa[k] * Wc[k*10 + c];
    out[g*10 + c] = acc;
  }
}

extern "C" void kernel_launch(void* const* d_in, const int* in_sizes, int n_in,
                              void* d_out, int out_size, void* d_ws, size_t ws_size,
                              hipStream_t stream) {
  const float* x      = (const float*)d_in[0];
  const float* lap    = (const float*)d_in[1];
  const float* rw     = (const float*)d_in[2];
  const int*   ei     = (const int*)d_in[3];
  const int*   batch  = (const int*)d_in[4];
  const float* Wp     = (const float*)d_in[5];
  const float* bp     = (const float*)d_in[6];
  const float* gin_W1 = (const float*)d_in[7];
  const float* gin_b1 = (const float*)d_in[8];
  const float* gin_W2 = (const float*)d_in[9];
  const float* gin_b2 = (const float*)d_in[10];
  const float* bn1_g  = (const float*)d_in[11];
  const float* bn1_b  = (const float*)d_in[12];
  const float* bn2_g  = (const float*)d_in[13];
  const float* bn2_b  = (const float*)d_in[14];
  const float* bn3_g  = (const float*)d_in[15];
  const float* bn3_b  = (const float*)d_in[16];
  const float* ain_w  = (const float*)d_in[17];
  const float* ain_b  = (const float*)d_in[18];
  const float* aout_w = (const float*)d_in[19];
  const float* aout_b = (const float*)d_in[20];
  const float* mlp_W1 = (const float*)d_in[21];
  const float* mlp_b1 = (const float*)d_in[22];
  const float* mlp_W2 = (const float*)d_in[23];
  const float* mlp_b2 = (const float*)d_in[24];
  const float* Wr1    = (const float*)d_in[25];
  const float* br1    = (const float*)d_in[26];
  const float* Wr2    = (const float*)d_in[27];
  const float* br2    = (const float*)d_in[28];
  const float* Wc     = (const float*)d_in[29];
  const float* bc     = (const float*)d_in[30];
  float* out = (float*)d_out;

  float* w = (float*)d_ws;
  float* h      = w + 0;          // 524288
  float* agg    = w + 524288;     // 524288
  float* gtmp   = w + 1048576;    // 524288
  float* pre1   = w + 1572864;    // 524288
  float* pre2   = w + 2097152;    // 524288
  float* mlph   = w + 2621440;    // 1048576
  float* out3   = w + 3670016;    // 524288
  u16*   opart  = (u16*)(w + 4194304);    // 4M u16 (bf16 partials)
  float* lpart  = w + 8388608;    // 131072
  float* stats  = w + 8519680;    // 1536 (2 layers x 768)   [zero region start]
  float* pooled = w + 8521216;    // 8192
  int*   cnt    = (int*)(w + 8529408);    // 4096             [zero region end]
  int*   rowptr = (int*)(w + 8533504);    // 4104
  int*   cursor = (int*)(w + 8537608);    // 4096
  int*   elist  = (int*)(w + 8541704);    // 65536
  u16*   wts    = (u16*)(w + 8607240);    // 344064 u16
  u16*   qb     = (u16*)(w + 8779272);
  u16*   kb     = (u16*)(w + 9041416);
  u16*   vt     = (u16*)(w + 9303560);

  u16* wpt = wts;
  u16 *qkvWt[2], *g1t[2], *g2t[2], *aot[2], *m1t[2], *m2t[2];
  {
    int off = 16384;
    for (int l = 0; l < 2; l++) {
      qkvWt[l] = wts + off; off += 384*128;
      g1t[l]   = wts + off; off += 128*128;
      g2t[l]   = wts + off; off += 128*128;
      aot[l]   = wts + off; off += 128*128;
      m1t[l]   = wts + off; off += 256*128;
      m2t[l]   = wts + off; off += 128*256;
    }
  }
  TPack tp;
  {
    int ti = 0, toff = 0;
    auto addm = [&](const float* s, int Ks, int Kd, int Md) {
      tp.d[ti].src = s; tp.d[ti].Ks = Ks; tp.d[ti].K = Kd; tp.d[ti].M = Md;
      tp.d[ti].off = toff; toff += Kd * Md; ti++;
    };
    addm(Wp, 88, 128, 128);
    for (int l = 0; l < 2; l++) {
      addm(ain_w + l*HH*384, 128, 128, 384);
      addm(gin_W1 + l*HH*HH, 128, 128, 128);
      addm(gin_W2 + l*HH*HH, 128, 128, 128);
      addm(aout_w + l*HH*HH, 128, 128, 128);
      addm(mlp_W1 + l*HH*256, 128, 128, 256);
      addm(mlp_W2 + l*256*HH, 256, 256, 128);
    }
  }

  auto GA = [&](const float* A, const float* A2, const float* A3, const u16* Bt,
                const float* bias, float* C, const float* res, const float* res2,
                float* st, const float* sb, const float* g1, const float* b1,
                const float* g2, const float* b2, const u16* op, const float* lp,
                u16* q, u16* k, u16* v, int K, int M) {
    GArgs a; a.A=A; a.A2=A2; a.A3=A3; a.Bt=Bt; a.bias=bias; a.C=C; a.res=res;
    a.res2=res2; a.stats=st; a.sbase=sb; a.pg1=g1; a.pb1=b1; a.pg2=g2; a.pb2=b2;
    a.opart=op; a.lpart=lp; a.qb=q; a.kb=k; a.vt=v; a.K=K; a.M=M; return a;
  };

  // one memset: stats(1536) + pooled(8192) + cnt(4096) contiguous
  hipMemsetAsync(stats, 0, 13824*sizeof(float), stream);
  transcount_k<<<1600, 256, 0, stream>>>(tp, wts, ei, cnt);
  scan_k<<<1, 256, 0, stream>>>(cnt, rowptr, cursor);
  // scatter (blocks 0-255) || input projection (blocks 256-511)
  k_scat_inp<<<512, 256, SMEM_GEMM, stream>>>(ei, cursor, elist,
      GA(x, lap, rw, wpt, bp, h, nullptr, nullptr, nullptr, nullptr,
         nullptr, nullptr, nullptr, nullptr, nullptr, nullptr,
         nullptr, nullptr, nullptr, 128, 128));

  for (int l = 0; l < 2; l++) {
    float* st1 = stats + l*768;
    float* st2 = st1 + 256;
    float* st3 = st1 + 512;

    aggcsr_k<<<NN/2, 256, 0, stream>>>(rowptr, elist, h, agg);

    // qkv projection (768 blocks) || gin layer-1 (256 blocks)
    k_qkv_gin1<<<1024, 256, SMEM_GEMM, stream>>>(
        GA(h, nullptr, nullptr, qkvWt[l], ain_b + l*384, nullptr, nullptr,
           nullptr, nullptr, nullptr, nullptr, nullptr, nullptr, nullptr,
           nullptr, nullptr, qb, kb, vt, 128, 384),
        GA(h, agg, nullptr, g1t[l], gin_b1 + l*HH, gtmp, nullptr, nullptr,
           nullptr, nullptr, nullptr, nullptr, nullptr, nullptr,
           nullptr, nullptr, nullptr, nullptr, nullptr, 128, 128));

    mfma_attn_k<<<dim3(KSPLIT, NN/128, 4), 256, 0, stream>>>(qb, kb, vt, opart, lpart);

    // gin layer-2 (+res h, stats1) || attn-out (inline merge, +res h, stats2)
    k_gin2_ao<<<512, 256, SMEM_GEMM, stream>>>(
        GA(gtmp, nullptr, nullptr, g2t[l], gin_b2 + l*HH, pre1, h, nullptr,
           st1, nullptr, nullptr, nullptr, nullptr, nullptr,
           nullptr, nullptr, nullptr, nullptr, nullptr, 128, 128),
        GA(nullptr, nullptr, nullptr, aot[l], aout_b + l*HH, pre2, h, nullptr,
           st2, nullptr, nullptr, nullptr, nullptr, nullptr,
           opart, lpart, nullptr, nullptr, nullptr, 128, 128));

    // FFN1 (BN affines staged from stats)
    k_gemm<2,0,1><<<dim3(128,4), 256, SMEM_GEMM, stream>>>(
        GA(pre1, pre2, nullptr, m1t[l], mlp_b1 + l*256, mlph, nullptr, nullptr,
           nullptr, st1, bn1_g + l*HH, bn1_b + l*HH, bn2_g + l*HH, bn2_b + l*HH,
           nullptr, nullptr, nullptr, nullptr, nullptr, 128, 256));
    // FFN2 (+BN(res)+BN(res2), stats3)
    k_gemm<0,3,0><<<dim3(128,2), 256, SMEM_GEMM, stream>>>(
        GA(mlph, nullptr, nullptr, m2t[l], mlp_b2 + l*HH, out3, pre1, pre2,
           st3, st1, bn1_g + l*HH, bn1_b + l*HH, bn2_g + l*HH, bn2_b + l*HH,
           nullptr, nullptr, nullptr, nullptr, nullptr, 256, 128));
    bn3_k<<<NN*HH/256, 256, 0, stream>>>(out3, st3, bn3_g + l*HH, bn3_b + l*HH,
                                         h, batch, pooled, l == 1);
  }

  head_k<<<GG, 128, 0, stream>>>(pooled, Wr1, br1, Wr2, br2, Wc, bc, out);
}